// Round 2
// baseline (406.986 us; speedup 1.0000x reference)
//
#include <hip/hip_runtime.h>
#include <hip/hip_bf16.h>

// CustomMHA (B=2,S=2048,D=1024,H=16,dh=64) for MI355X / gfx950.
//
// Pipeline:
//  1) cvt_split:  x, W_qkv f32 -> (hi,lo) bf16 pairs; W_o -> bf16.
//  2) gemm_qkv :  T = X @ Wqkv^T, split-bf16 (3 MFMA) for f32-level accuracy.
//     Epilogue scatters into Q(hi,lo), K(hi,lo) in (bh, s2, dh) layout and
//     V (plain bf16) TRANSPOSED as (bh, dh, s2)  [s2 = (s%128)*16 + d/64].
//  3) attn      :  per (bh, q-tile-of-128): causal flash attention in s2 space,
//     QK^T via 3-MFMA split (scores are sigma~256 -> softmax ~argmax, needs
//     f32-level scores), softmax f32, P,V bf16.  No block barriers (per-wave).
//  4) gemm_out  :  Y = Yp @ Wo^T, plain bf16, f32 output.

using bf16 = __hip_bfloat16;
typedef __attribute__((ext_vector_type(8))) short bf16x8v;   // 8 bf16 in 4 VGPRs
typedef __attribute__((ext_vector_type(4))) float f32x4;

#define MFMA_BF16(A, B, C) __builtin_amdgcn_mfma_f32_16x16x32_bf16((A), (B), (C), 0, 0, 0)

#define GLD_LDS16(g, l)                                                        \
  __builtin_amdgcn_global_load_lds(                                            \
      (const __attribute__((address_space(1))) void*)(g),                      \
      (__attribute__((address_space(3))) void*)(l), 16, 0, 0)

static __device__ __forceinline__ unsigned short bf_bits(float f) {
  bf16 b = __float2bfloat16(f);
  return *reinterpret_cast<unsigned short*>(&b);
}

// ---------------------------------------------------------------- converts --
__global__ __launch_bounds__(256) void cvt_split(const float* __restrict__ in,
                                                 bf16* __restrict__ hi,
                                                 bf16* __restrict__ lo, int n) {
  int i = (blockIdx.x * 256 + threadIdx.x) * 4;
  if (i >= n) return;
  const float4 v = *(const float4*)(in + i);
  float vv[4] = {v.x, v.y, v.z, v.w};
  ushort4 hb, lb;
  unsigned short* hp = &hb.x;
  unsigned short* lp = &lb.x;
#pragma unroll
  for (int j = 0; j < 4; ++j) {
    bf16 h = __float2bfloat16(vv[j]);
    float r = vv[j] - __bfloat162float(h);   // exact residual
    hp[j] = bf_bits(vv[j]);
    lp[j] = bf_bits(r);
  }
  *(ushort4*)(hi + i) = hb;
  *(ushort4*)(lo + i) = lb;
}

__global__ __launch_bounds__(256) void cvt_plain(const float* __restrict__ in,
                                                 bf16* __restrict__ out, int n) {
  int i = (blockIdx.x * 256 + threadIdx.x) * 4;
  if (i >= n) return;
  const float4 v = *(const float4*)(in + i);
  ushort4 ob;
  ob.x = bf_bits(v.x); ob.y = bf_bits(v.y); ob.z = bf_bits(v.z); ob.w = bf_bits(v.w);
  *(ushort4*)(out + i) = ob;
}

// ----------------------------------------------------------------- gemm_qkv --
// T[m,n] = sum_k X[m,k]*Wqkv[n,k], M=4096 N=3072 K=1024, split-bf16 inputs.
// 128x128 tile, 256 thr (4 waves, 2x2), BK=32, global_load_lds w=16.
__global__ __launch_bounds__(256) void gemm_qkv(
    const bf16* __restrict__ Ah, const bf16* __restrict__ Al,
    const bf16* __restrict__ Bh, const bf16* __restrict__ Bl,
    bf16* __restrict__ Qhi, bf16* __restrict__ Qlo,
    bf16* __restrict__ Khi, bf16* __restrict__ Klo,
    bf16* __restrict__ Vt) {
  const int K = 1024;
  const int NT = 24;  // 3072/128
  __shared__ __attribute__((aligned(16))) bf16 AsH[4096], AsL[4096], BsH[4096], BsL[4096];
  const int t = threadIdx.x;
  const int lane = t & 63;
  const int wave = t >> 6;
  const int wr = wave >> 1, wc = wave & 1;
  const int bm = blockIdx.x / NT, bn = blockIdx.x % NT;
  const int brow = bm * 128, bcol = bn * 128;
  const bf16* pAh = Ah + (size_t)brow * K;
  const bf16* pAl = Al + (size_t)brow * K;
  const bf16* pBh = Bh + (size_t)bcol * K;
  const bf16* pBl = Bl + (size_t)bcol * K;
  const int r0 = t >> 2;          // 0..63
  const int c0 = (t & 3) * 8;     // k offset of this thread's 16B chunk
  f32x4 acc[4][4] = {};
  for (int k0 = 0; k0 < K; k0 += 32) {
    __syncthreads();
    GLD_LDS16(pAh + (size_t)r0 * K + k0 + c0,        &AsH[t * 8]);
    GLD_LDS16(pAh + (size_t)(r0 + 64) * K + k0 + c0, &AsH[2048 + t * 8]);
    GLD_LDS16(pAl + (size_t)r0 * K + k0 + c0,        &AsL[t * 8]);
    GLD_LDS16(pAl + (size_t)(r0 + 64) * K + k0 + c0, &AsL[2048 + t * 8]);
    GLD_LDS16(pBh + (size_t)r0 * K + k0 + c0,        &BsH[t * 8]);
    GLD_LDS16(pBh + (size_t)(r0 + 64) * K + k0 + c0, &BsH[2048 + t * 8]);
    GLD_LDS16(pBl + (size_t)r0 * K + k0 + c0,        &BsL[t * 8]);
    GLD_LDS16(pBl + (size_t)(r0 + 64) * K + k0 + c0, &BsL[2048 + t * 8]);
    __syncthreads();
    bf16x8v ah[4], al[4], bh_[4], bl_[4];
    const int ao = (wr * 64 + (lane & 15)) * 32 + (lane >> 4) * 8;
    const int bo = (wc * 64 + (lane & 15)) * 32 + (lane >> 4) * 8;
#pragma unroll
    for (int i = 0; i < 4; ++i) {
      ah[i]  = *(const bf16x8v*)&AsH[ao + i * 512];
      al[i]  = *(const bf16x8v*)&AsL[ao + i * 512];
      bh_[i] = *(const bf16x8v*)&BsH[bo + i * 512];
      bl_[i] = *(const bf16x8v*)&BsL[bo + i * 512];
    }
#pragma unroll
    for (int i = 0; i < 4; ++i)
#pragma unroll
      for (int j = 0; j < 4; ++j) {
        acc[i][j] = MFMA_BF16(ah[i], bh_[j], acc[i][j]);
        acc[i][j] = MFMA_BF16(ah[i], bl_[j], acc[i][j]);
        acc[i][j] = MFMA_BF16(al[i], bh_[j], acc[i][j]);
      }
  }
  // epilogue: split + scatter into (bh, s2, dh) layout (V transposed).
#pragma unroll
  for (int i = 0; i < 4; ++i)
#pragma unroll
    for (int j = 0; j < 4; ++j)
#pragma unroll
      for (int e = 0; e < 4; ++e) {
        const int m = brow + wr * 64 + i * 16 + ((lane >> 4) << 2) + e;
        const int n = bcol + wc * 64 + j * 16 + (lane & 15);
        const float v = acc[i][j][e];
        const int b = m >> 11, s = m & 2047;
        const int c = n >> 10, d = n & 1023;
        const int bh_i = (b << 4) | (s >> 7);
        const int s2 = ((s & 127) << 4) | (d >> 6);
        const int dh = d & 63;
        if (c == 2) {
          Vt[((size_t)bh_i << 17) | ((size_t)dh << 11) | (size_t)s2] = __float2bfloat16(v);
        } else {
          const size_t idx = ((size_t)bh_i << 17) | ((size_t)s2 << 6) | (size_t)dh;
          bf16 hv = __float2bfloat16(v);
          bf16 lv = __float2bfloat16(v - __bfloat162float(hv));
          if (c == 0) { Qhi[idx] = hv; Qlo[idx] = lv; }
          else        { Khi[idx] = hv; Klo[idx] = lv; }
        }
      }
}

// --------------------------------------------------------------------- attn --
// Per block: one (bh) and one 128-row q-tile; 4 waves x 32 q-rows; fully
// wave-independent (no __syncthreads; per-wave LDS scratch for P).
// Swapped QK^T: st = K·Q^T so the softmax reduce is over lane-groups.
__global__ __launch_bounds__(256) void attn_kernel(
    const bf16* __restrict__ Qhi, const bf16* __restrict__ Qlo,
    const bf16* __restrict__ Khi, const bf16* __restrict__ Klo,
    const bf16* __restrict__ Vt, bf16* __restrict__ Yp) {
  const int wave = threadIdx.x >> 6;
  const int lane = threadIdx.x & 63;
  const int bh = blockIdx.x >> 4;
  const int qt = blockIdx.x & 15;
  const int b = bh >> 4, h = bh & 15;
  const size_t base = (size_t)bh << 17;  // * 2048*64
  const bf16* qh_p = Qhi + base;
  const bf16* ql_p = Qlo + base;
  const bf16* kh_p = Khi + base;
  const bf16* kl_p = Klo + base;
  const bf16* v_p  = Vt + base;          // (dh, s2) layout
  const int qbase = qt * 128 + wave * 32;
  const int l15 = lane & 15;
  const int lg = lane >> 4;              // 0..3
  __shared__ __attribute__((aligned(16))) bf16 Plds[4][32][72];

  // Q fragments (B-operand: col = q-row = l15, k = dh), loaded once.
  bf16x8v qfh[2][2], qfl[2][2];
#pragma unroll
  for (int i = 0; i < 2; ++i)
#pragma unroll
    for (int x2 = 0; x2 < 2; ++x2) {
      const size_t o = (size_t)(qbase + i * 16 + l15) * 64 + x2 * 32 + lg * 8;
      qfh[i][x2] = *(const bf16x8v*)(qh_p + o);
      qfl[i][x2] = *(const bf16x8v*)(ql_p + o);
    }
  f32x4 oac[2][4] = {};
  float mrun[2] = {-3.0e38f, -3.0e38f};
  float lrun[2] = {0.0f, 0.0f};
  const int ntiles = (qbase + 31) / 64 + 1;  // causal bound for this wave
  for (int kt = 0; kt < ntiles; ++kt) {
    const int kb = kt * 64;
    // ST = K · Q^T  (split: hh + h*l + l*h)
    f32x4 st[4][2] = {};
#pragma unroll
    for (int kf = 0; kf < 4; ++kf) {
      const size_t ko = (size_t)(kb + kf * 16 + l15) * 64 + lg * 8;
      const bf16x8v kh0 = *(const bf16x8v*)(kh_p + ko);
      const bf16x8v kh1 = *(const bf16x8v*)(kh_p + ko + 32);
      const bf16x8v kl0 = *(const bf16x8v*)(kl_p + ko);
      const bf16x8v kl1 = *(const bf16x8v*)(kl_p + ko + 32);
#pragma unroll
      for (int q2 = 0; q2 < 2; ++q2) {
        f32x4 a = st[kf][q2];
        a = MFMA_BF16(kh0, qfh[q2][0], a);
        a = MFMA_BF16(kh1, qfh[q2][1], a);
        a = MFMA_BF16(kh0, qfl[q2][0], a);
        a = MFMA_BF16(kh1, qfl[q2][1], a);
        a = MFMA_BF16(kl0, qfh[q2][0], a);
        a = MFMA_BF16(kl1, qfh[q2][1], a);
        st[kf][q2] = a;
      }
    }
    // scale + causal mask (in s2 space) + tile max
    float tmax[2] = {-3.0e38f, -3.0e38f};
#pragma unroll
    for (int kf = 0; kf < 4; ++kf)
#pragma unroll
      for (int q2 = 0; q2 < 2; ++q2)
#pragma unroll
        for (int e = 0; e < 4; ++e) {
          const int key = kb + kf * 16 + (lg << 2) + e;
          const int qr = qbase + q2 * 16 + l15;
          float sc = st[kf][q2][e] * 0.03125f;   // 1/sqrt(1024)
          sc = (key <= qr) ? sc : -3.0e38f;
          st[kf][q2][e] = sc;
          tmax[q2] = fmaxf(tmax[q2], sc);
        }
    float sfac[2];
#pragma unroll
    for (int q2 = 0; q2 < 2; ++q2) {
      float tm = tmax[q2];
      tm = fmaxf(tm, __shfl_xor(tm, 16));
      tm = fmaxf(tm, __shfl_xor(tm, 32));
      const float mn = fmaxf(mrun[q2], tm);
      sfac[q2] = exp2f((mrun[q2] - mn) * 1.4426950408889634f);
      mrun[q2] = mn;
    }
    float psum[2] = {0.0f, 0.0f};
#pragma unroll
    for (int kf = 0; kf < 4; ++kf)
#pragma unroll
      for (int q2 = 0; q2 < 2; ++q2)
#pragma unroll
        for (int e = 0; e < 4; ++e) {
          const float pv = exp2f((st[kf][q2][e] - mrun[q2]) * 1.4426950408889634f);
          psum[q2] += pv;
          Plds[wave][q2 * 16 + l15][kf * 16 + (lg << 2) + e] = __float2bfloat16(pv);
        }
#pragma unroll
    for (int q2 = 0; q2 < 2; ++q2) {
      float ps = psum[q2];
      ps += __shfl_xor(ps, 16);
      ps += __shfl_xor(ps, 32);
      lrun[q2] = lrun[q2] * sfac[q2] + ps;
#pragma unroll
      for (int e = 0; e < 4; ++e) {       // rescale O rows (row = lg*4+e)
        const float so = __shfl(sfac[q2], (lg << 2) + e);
#pragma unroll
        for (int df = 0; df < 4; ++df) oac[q2][df][e] *= so;
      }
    }
    // O += P · V   (A = P from LDS, B = V from transposed global layout)
#pragma unroll
    for (int x2 = 0; x2 < 2; ++x2) {
      bf16x8v pa[2];
#pragma unroll
      for (int q2 = 0; q2 < 2; ++q2)
        pa[q2] = *(const bf16x8v*)&Plds[wave][q2 * 16 + l15][x2 * 32 + lg * 8];
#pragma unroll
      for (int df = 0; df < 4; ++df) {
        const bf16x8v vb =
            *(const bf16x8v*)(v_p + (size_t)(df * 16 + l15) * 2048 + kb + x2 * 32 + lg * 8);
#pragma unroll
        for (int q2 = 0; q2 < 2; ++q2)
          oac[q2][df] = MFMA_BF16(pa[q2], vb, oac[q2][df]);
      }
    }
  }
  // epilogue: divide by softmax denom, write Yp (row = b*2048+s2, col = h*64+dh)
#pragma unroll
  for (int q2 = 0; q2 < 2; ++q2) {
    float li[4];
#pragma unroll
    for (int e = 0; e < 4; ++e) li[e] = 1.0f / __shfl(lrun[q2], (lg << 2) + e);
#pragma unroll
    for (int df = 0; df < 4; ++df)
#pragma unroll
      for (int e = 0; e < 4; ++e) {
        const int qr = qbase + q2 * 16 + (lg << 2) + e;
        const int dh = df * 16 + l15;
        Yp[(size_t)(b * 2048 + qr) * 1024 + h * 64 + dh] =
            __float2bfloat16(oac[q2][df][e] * li[e]);
      }
  }
}

// ----------------------------------------------------------------- gemm_out --
// Y[m,n] = sum_k Yp[m,k]*Wo[n,k], M=4096 N=1024 K=1024, plain bf16, f32 out.
__global__ __launch_bounds__(256) void gemm_out(const bf16* __restrict__ A,
                                                const bf16* __restrict__ B,
                                                float* __restrict__ C) {
  const int K = 1024;
  const int NT = 8;  // 1024/128
  __shared__ __attribute__((aligned(16))) bf16 As[4096], Bs[4096];
  const int t = threadIdx.x;
  const int lane = t & 63;
  const int wave = t >> 6;
  const int wr = wave >> 1, wc = wave & 1;
  const int bm = blockIdx.x / NT, bn = blockIdx.x % NT;
  const int brow = bm * 128, bcol = bn * 128;
  const bf16* pA = A + (size_t)brow * K;
  const bf16* pB = B + (size_t)bcol * K;
  const int r0 = t >> 2;
  const int c0 = (t & 3) * 8;
  f32x4 acc[4][4] = {};
  for (int k0 = 0; k0 < K; k0 += 32) {
    __syncthreads();
    GLD_LDS16(pA + (size_t)r0 * K + k0 + c0,        &As[t * 8]);
    GLD_LDS16(pA + (size_t)(r0 + 64) * K + k0 + c0, &As[2048 + t * 8]);
    GLD_LDS16(pB + (size_t)r0 * K + k0 + c0,        &Bs[t * 8]);
    GLD_LDS16(pB + (size_t)(r0 + 64) * K + k0 + c0, &Bs[2048 + t * 8]);
    __syncthreads();
    bf16x8v af[4], bf_[4];
    const int ao = (wr * 64 + (lane & 15)) * 32 + (lane >> 4) * 8;
    const int bo = (wc * 64 + (lane & 15)) * 32 + (lane >> 4) * 8;
#pragma unroll
    for (int i = 0; i < 4; ++i) {
      af[i]  = *(const bf16x8v*)&As[ao + i * 512];
      bf_[i] = *(const bf16x8v*)&Bs[bo + i * 512];
    }
#pragma unroll
    for (int i = 0; i < 4; ++i)
#pragma unroll
      for (int j = 0; j < 4; ++j)
        acc[i][j] = MFMA_BF16(af[i], bf_[j], acc[i][j]);
  }
#pragma unroll
  for (int i = 0; i < 4; ++i)
#pragma unroll
    for (int j = 0; j < 4; ++j)
#pragma unroll
      for (int e = 0; e < 4; ++e) {
        const int m = brow + wr * 64 + i * 16 + ((lane >> 4) << 2) + e;
        const int n = bcol + wc * 64 + j * 16 + (lane & 15);
        C[(size_t)m * 1024 + n] = acc[i][j][e];
      }
}

// -------------------------------------------------------------------- launch --
extern "C" void kernel_launch(void* const* d_in, const int* in_sizes, int n_in,
                              void* d_out, int out_size, void* d_ws, size_t ws_size,
                              hipStream_t stream) {
  (void)in_sizes; (void)n_in; (void)out_size; (void)ws_size;
  const float* x    = (const float*)d_in[0];
  const float* wqkv = (const float*)d_in[1];
  const float* wo   = (const float*)d_in[2];
  float* out = (float*)d_out;

  const size_t NX = 4096ull * 1024;   // x / per-tensor QKV / Yp elements
  const size_t NW = 3072ull * 1024;   // W_qkv elements
  const size_t NO = 1024ull * 1024;   // W_o elements

  bf16* p = (bf16*)d_ws;
  bf16* xh  = p; p += NX;
  bf16* xl  = p; p += NX;
  bf16* wqh = p; p += NW;
  bf16* wql = p; p += NW;
  bf16* wob = p; p += NO;
  bf16* qhi = p; p += NX;
  bf16* qlo = p; p += NX;
  bf16* khi = p; p += NX;
  bf16* klo = p; p += NX;
  bf16* vt  = p; p += NX;
  bf16* yp  = p; p += NX;   // total ~78 MB of workspace

  hipLaunchKernelGGL(cvt_split, dim3(NX / 1024), dim3(256), 0, stream, x, xh, xl, (int)NX);
  hipLaunchKernelGGL(cvt_split, dim3(NW / 1024), dim3(256), 0, stream, wqkv, wqh, wql, (int)NW);
  hipLaunchKernelGGL(cvt_plain, dim3(NO / 1024), dim3(256), 0, stream, wo, wob, (int)NO);
  hipLaunchKernelGGL(gemm_qkv, dim3(32 * 24), dim3(256), 0, stream,
                     xh, xl, wqh, wql, qhi, qlo, khi, klo, vt);
  hipLaunchKernelGGL(attn_kernel, dim3(512), dim3(256), 0, stream,
                     qhi, qlo, khi, klo, vt, yp);
  hipLaunchKernelGGL(gemm_out, dim3(32 * 8), dim3(256), 0, stream, yp, wob, out);
}

// Round 4
// 337.605 us; speedup vs baseline: 1.2055x; 1.2055x over previous
//
#include <hip/hip_runtime.h>
#include <hip/hip_bf16.h>

// CustomMHA (B=2,S=2048,D=1024,H=16,dh=64) for MI355X / gfx950.
//
// Pipeline:
//  1) cvt_split:  x, W_qkv f32 -> (hi,lo) bf16 pairs; W_o -> bf16.
//  2) gemm_qkv :  T = X @ Wqkv^T, split-bf16 (3 MFMA) for f32-level accuracy.
//     Epilogue scatters into Q(hi,lo) [pre-scaled by 1/sqrt(D)], K(hi,lo) in
//     (bh, s2, dh) layout and V (plain bf16) TRANSPOSED as (bh, dh, s2).
//  3) attn      :  1-wave blocks, 32 q-rows each, longest-first dispatch.
//     Causal flash attention in s2 space; QK^T via 3-MFMA split; softmax f32
//     with defer-max; denominator accumulated via MFMA against a ones vector.
//     __syncthreads() fences the cross-lane LDS handoff of P (the per-thread
//     LLVM memory model cannot see lane-crossed ds_write->ds_read deps).
//  4) gemm_out  :  Y = Yp @ Wo^T, plain bf16, f32 output.

using bf16 = __hip_bfloat16;
typedef __attribute__((ext_vector_type(8))) short bf16x8v;   // 8 bf16 in 4 VGPRs
typedef __attribute__((ext_vector_type(4))) float f32x4;

#define MFMA_BF16(A, B, C) __builtin_amdgcn_mfma_f32_16x16x32_bf16((A), (B), (C), 0, 0, 0)

#define GLD_LDS16(g, l)                                                        \
  __builtin_amdgcn_global_load_lds(                                            \
      (const __attribute__((address_space(1))) void*)(g),                      \
      (__attribute__((address_space(3))) void*)(l), 16, 0, 0)

static __device__ __forceinline__ unsigned short bf_bits(float f) {
  bf16 b = __float2bfloat16(f);
  return *reinterpret_cast<unsigned short*>(&b);
}

// ---------------------------------------------------------------- converts --
__global__ __launch_bounds__(256) void cvt_split(const float* __restrict__ in,
                                                 bf16* __restrict__ hi,
                                                 bf16* __restrict__ lo, int n) {
  int i = (blockIdx.x * 256 + threadIdx.x) * 4;
  if (i >= n) return;
  const float4 v = *(const float4*)(in + i);
  float vv[4] = {v.x, v.y, v.z, v.w};
  ushort4 hb, lb;
  unsigned short* hp = &hb.x;
  unsigned short* lp = &lb.x;
#pragma unroll
  for (int j = 0; j < 4; ++j) {
    bf16 h = __float2bfloat16(vv[j]);
    float r = vv[j] - __bfloat162float(h);   // exact residual
    hp[j] = bf_bits(vv[j]);
    lp[j] = bf_bits(r);
  }
  *(ushort4*)(hi + i) = hb;
  *(ushort4*)(lo + i) = lb;
}

__global__ __launch_bounds__(256) void cvt_plain(const float* __restrict__ in,
                                                 bf16* __restrict__ out, int n) {
  int i = (blockIdx.x * 256 + threadIdx.x) * 4;
  if (i >= n) return;
  const float4 v = *(const float4*)(in + i);
  ushort4 ob;
  ob.x = bf_bits(v.x); ob.y = bf_bits(v.y); ob.z = bf_bits(v.z); ob.w = bf_bits(v.w);
  *(ushort4*)(out + i) = ob;
}

// ----------------------------------------------------------------- gemm_qkv --
// T[m,n] = sum_k X[m,k]*Wqkv[n,k], M=4096 N=3072 K=1024, split-bf16 inputs.
// 128x128 tile, 256 thr (4 waves, 2x2), BK=32, global_load_lds w=16.
__global__ __launch_bounds__(256) void gemm_qkv(
    const bf16* __restrict__ Ah, const bf16* __restrict__ Al,
    const bf16* __restrict__ Bh, const bf16* __restrict__ Bl,
    bf16* __restrict__ Qhi, bf16* __restrict__ Qlo,
    bf16* __restrict__ Khi, bf16* __restrict__ Klo,
    bf16* __restrict__ Vt) {
  const int K = 1024;
  const int NT = 24;  // 3072/128
  __shared__ __attribute__((aligned(16))) bf16 AsH[4096], AsL[4096], BsH[4096], BsL[4096];
  const int t = threadIdx.x;
  const int lane = t & 63;
  const int wave = t >> 6;
  const int wr = wave >> 1, wc = wave & 1;
  // bijective XCD swizzle (768 % 8 == 0)
  int bid = blockIdx.x;
  bid = (bid & 7) * (768 >> 3) + (bid >> 3);
  const int bm = bid / NT, bn = bid % NT;
  const int brow = bm * 128, bcol = bn * 128;
  const bf16* pAh = Ah + (size_t)brow * K;
  const bf16* pAl = Al + (size_t)brow * K;
  const bf16* pBh = Bh + (size_t)bcol * K;
  const bf16* pBl = Bl + (size_t)bcol * K;
  const int r0 = t >> 2;          // 0..63
  const int c0 = (t & 3) * 8;     // k offset of this thread's 16B chunk
  f32x4 acc[4][4] = {};
  for (int k0 = 0; k0 < K; k0 += 32) {
    __syncthreads();
    GLD_LDS16(pAh + (size_t)r0 * K + k0 + c0,        &AsH[t * 8]);
    GLD_LDS16(pAh + (size_t)(r0 + 64) * K + k0 + c0, &AsH[2048 + t * 8]);
    GLD_LDS16(pAl + (size_t)r0 * K + k0 + c0,        &AsL[t * 8]);
    GLD_LDS16(pAl + (size_t)(r0 + 64) * K + k0 + c0, &AsL[2048 + t * 8]);
    GLD_LDS16(pBh + (size_t)r0 * K + k0 + c0,        &BsH[t * 8]);
    GLD_LDS16(pBh + (size_t)(r0 + 64) * K + k0 + c0, &BsH[2048 + t * 8]);
    GLD_LDS16(pBl + (size_t)r0 * K + k0 + c0,        &BsL[t * 8]);
    GLD_LDS16(pBl + (size_t)(r0 + 64) * K + k0 + c0, &BsL[2048 + t * 8]);
    __syncthreads();
    bf16x8v ah[4], al[4], bh_[4], bl_[4];
    const int ao = (wr * 64 + (lane & 15)) * 32 + (lane >> 4) * 8;
    const int bo = (wc * 64 + (lane & 15)) * 32 + (lane >> 4) * 8;
#pragma unroll
    for (int i = 0; i < 4; ++i) {
      ah[i]  = *(const bf16x8v*)&AsH[ao + i * 512];
      al[i]  = *(const bf16x8v*)&AsL[ao + i * 512];
      bh_[i] = *(const bf16x8v*)&BsH[bo + i * 512];
      bl_[i] = *(const bf16x8v*)&BsL[bo + i * 512];
    }
#pragma unroll
    for (int i = 0; i < 4; ++i)
#pragma unroll
      for (int j = 0; j < 4; ++j) {
        acc[i][j] = MFMA_BF16(ah[i], bh_[j], acc[i][j]);
        acc[i][j] = MFMA_BF16(ah[i], bl_[j], acc[i][j]);
        acc[i][j] = MFMA_BF16(al[i], bh_[j], acc[i][j]);
      }
  }
  // epilogue: split + scatter into (bh, s2, dh) layout (V transposed).
  // Q gets the 1/sqrt(D)=1/32 softmax scale folded in (exact pow-2 scale).
#pragma unroll
  for (int i = 0; i < 4; ++i)
#pragma unroll
    for (int j = 0; j < 4; ++j)
#pragma unroll
      for (int e = 0; e < 4; ++e) {
        const int m = brow + wr * 64 + i * 16 + ((lane >> 4) << 2) + e;
        const int n = bcol + wc * 64 + j * 16 + (lane & 15);
        float v = acc[i][j][e];
        const int b = m >> 11, s = m & 2047;
        const int c = n >> 10, d = n & 1023;
        const int bh_i = (b << 4) | (s >> 7);
        const int s2 = ((s & 127) << 4) | (d >> 6);
        const int dh = d & 63;
        if (c == 2) {
          Vt[((size_t)bh_i << 17) | ((size_t)dh << 11) | (size_t)s2] = __float2bfloat16(v);
        } else {
          if (c == 0) v *= 0.03125f;   // fold 1/sqrt(1024) into Q
          const size_t idx = ((size_t)bh_i << 17) | ((size_t)s2 << 6) | (size_t)dh;
          bf16 hv = __float2bfloat16(v);
          bf16 lv = __float2bfloat16(v - __bfloat162float(hv));
          if (c == 0) { Qhi[idx] = hv; Qlo[idx] = lv; }
          else        { Khi[idx] = hv; Klo[idx] = lv; }
        }
      }
}

// --------------------------------------------------------------------- attn --
// 1 wave / block; block = (bh, 32-row q-chunk). Longest chunks dispatch first.
// Swapped QK^T (st = K·Q^T) so softmax reduce is a 2-shuffle xor; denominator
// accumulated via MFMA(P, ones) into a C-layout-matched accumulator; defer-max
// (THR=8) skips the O-rescale on almost every tile.
__global__ __launch_bounds__(64) void attn_kernel(
    const bf16* __restrict__ Qhi, const bf16* __restrict__ Qlo,
    const bf16* __restrict__ Khi, const bf16* __restrict__ Klo,
    const bf16* __restrict__ Vt, bf16* __restrict__ Yp) {
  const int lane = threadIdx.x & 63;
  const int bh = blockIdx.x & 31;          // bh minor
  const int c  = 63 - (blockIdx.x >> 5);   // chunk, longest (c=63) first
  const int b = bh >> 4, h = bh & 15;
  const size_t base = (size_t)bh << 17;    // * 2048*64
  const bf16* qh_p = Qhi + base;
  const bf16* ql_p = Qlo + base;
  const bf16* kh_p = Khi + base;
  const bf16* kl_p = Klo + base;
  const bf16* v_p  = Vt + base;            // (dh, s2) layout
  const int qbase = c << 5;
  const int l15 = lane & 15;
  const int lg  = lane >> 4;               // 0..3
  __shared__ __attribute__((aligned(16))) bf16 Plds[32][72];

  // Q fragments (B-operand: col = q-row = l15, k = dh), loaded once.
  bf16x8v qfh[2][2], qfl[2][2];
#pragma unroll
  for (int q2 = 0; q2 < 2; ++q2)
#pragma unroll
    for (int x2 = 0; x2 < 2; ++x2) {
      const size_t o = (size_t)(qbase + q2 * 16 + l15) * 64 + x2 * 32 + lg * 8;
      qfh[q2][x2] = *(const bf16x8v*)(qh_p + o);
      qfl[q2][x2] = *(const bf16x8v*)(ql_p + o);
    }
  bf16x8v ones8;
#pragma unroll
  for (int j = 0; j < 8; ++j) ones8[j] = (short)0x3F80;  // bf16 1.0

  f32x4 oac[2][4] = {};
  f32x4 oden[2] = {};
  float mrun[2] = {-3.0e38f, -3.0e38f};
  const float L2E = 1.4426950408889634f;
  const int nfull = c >> 1;                // diagonal tile index

  for (int kt = 0; kt <= nfull; ++kt) {
    const int kb = kt << 6;
    // ST = K · Q^T  (split: hh + h*l + l*h); Q pre-scaled by 1/32.
    f32x4 st[4][2] = {};
#pragma unroll
    for (int kf = 0; kf < 4; ++kf) {
      const size_t ko = (size_t)(kb + kf * 16 + l15) * 64 + lg * 8;
      const bf16x8v kh0 = *(const bf16x8v*)(kh_p + ko);
      const bf16x8v kh1 = *(const bf16x8v*)(kh_p + ko + 32);
      const bf16x8v kl0 = *(const bf16x8v*)(kl_p + ko);
      const bf16x8v kl1 = *(const bf16x8v*)(kl_p + ko + 32);
#pragma unroll
      for (int q2 = 0; q2 < 2; ++q2) {
        f32x4 a = st[kf][q2];
        a = MFMA_BF16(kh0, qfh[q2][0], a);
        a = MFMA_BF16(kh1, qfh[q2][1], a);
        a = MFMA_BF16(kh0, qfl[q2][0], a);
        a = MFMA_BF16(kh1, qfl[q2][1], a);
        a = MFMA_BF16(kl0, qfh[q2][0], a);
        a = MFMA_BF16(kl1, qfh[q2][1], a);
        st[kf][q2] = a;
      }
    }
    // causal mask only on the diagonal tile
    if (kt == nfull) {
#pragma unroll
      for (int kf = 0; kf < 4; ++kf)
#pragma unroll
        for (int q2 = 0; q2 < 2; ++q2)
#pragma unroll
          for (int e = 0; e < 4; ++e) {
            const int key = kb + kf * 16 + (lg << 2) + e;
            const int qr  = qbase + q2 * 16 + l15;
            if (key > qr) st[kf][q2][e] = -3.0e38f;
          }
    }
    // per-column tile max
    float tmax[2] = {-3.0e38f, -3.0e38f};
#pragma unroll
    for (int kf = 0; kf < 4; ++kf)
#pragma unroll
      for (int q2 = 0; q2 < 2; ++q2)
#pragma unroll
        for (int e = 0; e < 4; ++e)
          tmax[q2] = fmaxf(tmax[q2], st[kf][q2][e]);
#pragma unroll
    for (int q2 = 0; q2 < 2; ++q2) {
      tmax[q2] = fmaxf(tmax[q2], __shfl_xor(tmax[q2], 16));
      tmax[q2] = fmaxf(tmax[q2], __shfl_xor(tmax[q2], 32));
    }
    // defer-max: rescale only if some column grew past mrun+8
    const int ok = (tmax[0] <= mrun[0] + 8.0f) && (tmax[1] <= mrun[1] + 8.0f);
    if (!__all(ok)) {
      float sfac[2];
#pragma unroll
      for (int q2 = 0; q2 < 2; ++q2) {
        const float mn = fmaxf(mrun[q2], tmax[q2]);
        sfac[q2] = exp2f((mrun[q2] - mn) * L2E);
        mrun[q2] = mn;
      }
#pragma unroll
      for (int q2 = 0; q2 < 2; ++q2)
#pragma unroll
        for (int e = 0; e < 4; ++e) {
          const float so = __shfl(sfac[q2], (lg << 2) + e);  // col -> row bcast
          oden[q2][e] *= so;
#pragma unroll
          for (int df = 0; df < 4; ++df) oac[q2][df][e] *= so;
        }
    }
    // P = exp2((s - m)*log2e), packed b64 writes into LDS
    const float mL0 = mrun[0] * L2E, mL1 = mrun[1] * L2E;
#pragma unroll
    for (int kf = 0; kf < 4; ++kf)
#pragma unroll
      for (int q2 = 0; q2 < 2; ++q2) {
        const float mL = q2 ? mL1 : mL0;
        ushort4 pk;
        unsigned short* pp = &pk.x;
#pragma unroll
        for (int e = 0; e < 4; ++e) {
          const float pv = exp2f(fmaf(st[kf][q2][e], L2E, -mL));
          pp[e] = bf_bits(pv);
        }
        *(ushort4*)&Plds[q2 * 16 + l15][kf * 16 + (lg << 2)] = pk;
      }
    // FENCE the cross-lane LDS handoff: lanes read P written by OTHER lanes;
    // per-thread alias analysis cannot order this (write/read offsets are
    // disjoint for lg!=0), so force lgkmcnt(0) + memory ordering explicitly.
    __syncthreads();
    // O += P · V ; den += P · 1
#pragma unroll
    for (int x2 = 0; x2 < 2; ++x2) {
      bf16x8v pa[2];
#pragma unroll
      for (int q2 = 0; q2 < 2; ++q2)
        pa[q2] = *(const bf16x8v*)&Plds[q2 * 16 + l15][x2 * 32 + lg * 8];
#pragma unroll
      for (int q2 = 0; q2 < 2; ++q2)
        oden[q2] = MFMA_BF16(pa[q2], ones8, oden[q2]);
#pragma unroll
      for (int df = 0; df < 4; ++df) {
        const bf16x8v vb =
            *(const bf16x8v*)(v_p + (size_t)(df * 16 + l15) * 2048 + kb + x2 * 32 + lg * 8);
#pragma unroll
        for (int q2 = 0; q2 < 2; ++q2)
          oac[q2][df] = MFMA_BF16(pa[q2], vb, oac[q2][df]);
      }
    }
  }
  // epilogue: oden rows match oac rows exactly -> no shuffles needed
#pragma unroll
  for (int q2 = 0; q2 < 2; ++q2) {
    float li[4];
#pragma unroll
    for (int e = 0; e < 4; ++e) li[e] = 1.0f / oden[q2][e];
#pragma unroll
    for (int df = 0; df < 4; ++df)
#pragma unroll
      for (int e = 0; e < 4; ++e) {
        const int qr = qbase + q2 * 16 + (lg << 2) + e;
        const int dh = df * 16 + l15;
        Yp[(size_t)(b * 2048 + qr) * 1024 + h * 64 + dh] =
            __float2bfloat16(oac[q2][df][e] * li[e]);
      }
  }
}

// ----------------------------------------------------------------- gemm_out --
// Y[m,n] = sum_k Yp[m,k]*Wo[n,k], M=4096 N=1024 K=1024, plain bf16, f32 out.
__global__ __launch_bounds__(256) void gemm_out(const bf16* __restrict__ A,
                                                const bf16* __restrict__ B,
                                                float* __restrict__ C) {
  const int K = 1024;
  const int NT = 8;  // 1024/128
  __shared__ __attribute__((aligned(16))) bf16 As[4096], Bs[4096];
  const int t = threadIdx.x;
  const int lane = t & 63;
  const int wave = t >> 6;
  const int wr = wave >> 1, wc = wave & 1;
  int bid = blockIdx.x;
  bid = (bid & 7) * (256 >> 3) + (bid >> 3);   // bijective XCD swizzle
  const int bm = bid / NT, bn = bid % NT;
  const int brow = bm * 128, bcol = bn * 128;
  const bf16* pA = A + (size_t)brow * K;
  const bf16* pB = B + (size_t)bcol * K;
  const int r0 = t >> 2;
  const int c0 = (t & 3) * 8;
  f32x4 acc[4][4] = {};
  for (int k0 = 0; k0 < K; k0 += 32) {
    __syncthreads();
    GLD_LDS16(pA + (size_t)r0 * K + k0 + c0,        &As[t * 8]);
    GLD_LDS16(pA + (size_t)(r0 + 64) * K + k0 + c0, &As[2048 + t * 8]);
    GLD_LDS16(pB + (size_t)r0 * K + k0 + c0,        &Bs[t * 8]);
    GLD_LDS16(pB + (size_t)(r0 + 64) * K + k0 + c0, &Bs[2048 + t * 8]);
    __syncthreads();
    bf16x8v af[4], bf_[4];
    const int ao = (wr * 64 + (lane & 15)) * 32 + (lane >> 4) * 8;
    const int bo = (wc * 64 + (lane & 15)) * 32 + (lane >> 4) * 8;
#pragma unroll
    for (int i = 0; i < 4; ++i) {
      af[i]  = *(const bf16x8v*)&As[ao + i * 512];
      bf_[i] = *(const bf16x8v*)&Bs[bo + i * 512];
    }
#pragma unroll
    for (int i = 0; i < 4; ++i)
#pragma unroll
      for (int j = 0; j < 4; ++j)
        acc[i][j] = MFMA_BF16(af[i], bf_[j], acc[i][j]);
  }
#pragma unroll
  for (int i = 0; i < 4; ++i)
#pragma unroll
    for (int j = 0; j < 4; ++j)
#pragma unroll
      for (int e = 0; e < 4; ++e) {
        const int m = brow + wr * 64 + i * 16 + ((lane >> 4) << 2) + e;
        const int n = bcol + wc * 64 + j * 16 + (lane & 15);
        C[(size_t)m * 1024 + n] = acc[i][j][e];
      }
}

// -------------------------------------------------------------------- launch --
extern "C" void kernel_launch(void* const* d_in, const int* in_sizes, int n_in,
                              void* d_out, int out_size, void* d_ws, size_t ws_size,
                              hipStream_t stream) {
  (void)in_sizes; (void)n_in; (void)out_size; (void)ws_size;
  const float* x    = (const float*)d_in[0];
  const float* wqkv = (const float*)d_in[1];
  const float* wo   = (const float*)d_in[2];
  float* out = (float*)d_out;

  const size_t NX = 4096ull * 1024;   // x / per-tensor QKV / Yp elements
  const size_t NW = 3072ull * 1024;   // W_qkv elements
  const size_t NO = 1024ull * 1024;   // W_o elements

  bf16* p = (bf16*)d_ws;
  bf16* xh  = p; p += NX;
  bf16* xl  = p; p += NX;
  bf16* wqh = p; p += NW;
  bf16* wql = p; p += NW;
  bf16* wob = p; p += NO;
  bf16* qhi = p; p += NX;
  bf16* qlo = p; p += NX;
  bf16* khi = p; p += NX;
  bf16* klo = p; p += NX;
  bf16* vt  = p; p += NX;
  bf16* yp  = p; p += NX;   // total ~78 MB of workspace

  hipLaunchKernelGGL(cvt_split, dim3(NX / 1024), dim3(256), 0, stream, x, xh, xl, (int)NX);
  hipLaunchKernelGGL(cvt_split, dim3(NW / 1024), dim3(256), 0, stream, wqkv, wqh, wql, (int)NW);
  hipLaunchKernelGGL(cvt_plain, dim3(NO / 1024), dim3(256), 0, stream, wo, wob, (int)NO);
  hipLaunchKernelGGL(gemm_qkv, dim3(32 * 24), dim3(256), 0, stream,
                     xh, xl, wqh, wql, qhi, qlo, khi, klo, vt);
  hipLaunchKernelGGL(attn_kernel, dim3(2048), dim3(64), 0, stream,
                     qhi, qlo, khi, klo, vt, yp);
  hipLaunchKernelGGL(gemm_out, dim3(32 * 8), dim3(256), 0, stream, yp, wob, out);
}

// Round 6
// 320.327 us; speedup vs baseline: 1.2705x; 1.0539x over previous
//
#include <hip/hip_runtime.h>
#include <hip/hip_bf16.h>

// CustomMHA (B=2,S=2048,D=1024,H=16,dh=64) for MI355X / gfx950.
//
// Pipeline:
//  1) cvt_split:  x, W_qkv f32 -> (hi,lo) bf16 pairs; W_o -> bf16.
//  2) gemm_qkv :  T = X @ Wqkv^T, split-bf16 (3 MFMA) for f32-level accuracy;
//     pure-V column tiles (bcol>=2048) use plain bf16 (1 MFMA, no lo loads).
//     Epilogue scatters into Q(hi,lo) [pre-scaled by 1/sqrt(D)], K(hi,lo) in
//     (bh, s2, dh) layout and V (plain bf16) TRANSPOSED as (bh, dh, s2).
//  3) attn      :  1-wave blocks, 32 q-rows each, longest-first dispatch.
//     Causal flash attention in s2 space; QK^T via 3-MFMA split; softmax f32
//     with defer-max; denominator via MFMA against ones. Software-pipelined:
//     V(t) and K(t+1) loads issue before the softmax; the P handoff is fenced
//     with lgkmcnt(0) only (NO vmcnt drain -> loads stay in flight).
//  4) gemm_out  :  Y = Yp @ Wo^T, plain bf16, f32 output.

using bf16 = __hip_bfloat16;
typedef __attribute__((ext_vector_type(8))) short bf16x8v;   // 8 bf16 in 4 VGPRs
typedef __attribute__((ext_vector_type(4))) float f32x4;

#define MFMA_BF16(A, B, C) __builtin_amdgcn_mfma_f32_16x16x32_bf16((A), (B), (C), 0, 0, 0)

#define GLD_LDS16(g, l)                                                        \
  __builtin_amdgcn_global_load_lds(                                            \
      (const __attribute__((address_space(1))) void*)(g),                      \
      (__attribute__((address_space(3))) void*)(l), 16, 0, 0)

static __device__ __forceinline__ unsigned short bf_bits(float f) {
  bf16 b = __float2bfloat16(f);
  return *reinterpret_cast<unsigned short*>(&b);
}

// ---------------------------------------------------------------- converts --
__global__ __launch_bounds__(256) void cvt_split(const float* __restrict__ in,
                                                 bf16* __restrict__ hi,
                                                 bf16* __restrict__ lo, int n) {
  int i = (blockIdx.x * 256 + threadIdx.x) * 4;
  if (i >= n) return;
  const float4 v = *(const float4*)(in + i);
  float vv[4] = {v.x, v.y, v.z, v.w};
  ushort4 hb, lb;
  unsigned short* hp = &hb.x;
  unsigned short* lp = &lb.x;
#pragma unroll
  for (int j = 0; j < 4; ++j) {
    bf16 h = __float2bfloat16(vv[j]);
    float r = vv[j] - __bfloat162float(h);   // exact residual
    hp[j] = bf_bits(vv[j]);
    lp[j] = bf_bits(r);
  }
  *(ushort4*)(hi + i) = hb;
  *(ushort4*)(lo + i) = lb;
}

__global__ __launch_bounds__(256) void cvt_plain(const float* __restrict__ in,
                                                 bf16* __restrict__ out, int n) {
  int i = (blockIdx.x * 256 + threadIdx.x) * 4;
  if (i >= n) return;
  const float4 v = *(const float4*)(in + i);
  ushort4 ob;
  ob.x = bf_bits(v.x); ob.y = bf_bits(v.y); ob.z = bf_bits(v.z); ob.w = bf_bits(v.w);
  *(ushort4*)(out + i) = ob;
}

// ----------------------------------------------------------------- gemm_qkv --
// T[m,n] = sum_k X[m,k]*Wqkv[n,k], M=4096 N=3072 K=1024, split-bf16 inputs.
// 128x128 tile, 256 thr (4 waves, 2x2), BK=32, global_load_lds w=16.
// Pure-V tiles (bcol>=2048) need only bf16 accuracy: 1 MFMA, no lo staging.
__global__ __launch_bounds__(256) void gemm_qkv(
    const bf16* __restrict__ Ah, const bf16* __restrict__ Al,
    const bf16* __restrict__ Bh, const bf16* __restrict__ Bl,
    bf16* __restrict__ Qhi, bf16* __restrict__ Qlo,
    bf16* __restrict__ Khi, bf16* __restrict__ Klo,
    bf16* __restrict__ Vt) {
  const int K = 1024;
  const int NT = 24;  // 3072/128
  __shared__ __attribute__((aligned(16))) bf16 AsH[4096], AsL[4096], BsH[4096], BsL[4096];
  const int t = threadIdx.x;
  const int lane = t & 63;
  const int wave = t >> 6;
  const int wr = wave >> 1, wc = wave & 1;
  // bijective XCD swizzle (768 % 8 == 0)
  int bid = blockIdx.x;
  bid = (bid & 7) * (768 >> 3) + (bid >> 3);
  const int bm = bid / NT, bn = bid % NT;
  const int brow = bm * 128, bcol = bn * 128;
  const bool isV = (bcol >= 2048);        // pure-V column tile (block-uniform)
  const bf16* pAh = Ah + (size_t)brow * K;
  const bf16* pAl = Al + (size_t)brow * K;
  const bf16* pBh = Bh + (size_t)bcol * K;
  const bf16* pBl = Bl + (size_t)bcol * K;
  const int r0 = t >> 2;          // 0..63
  const int c0 = (t & 3) * 8;     // k offset of this thread's 16B chunk
  f32x4 acc[4][4] = {};
  for (int k0 = 0; k0 < K; k0 += 32) {
    __syncthreads();
    GLD_LDS16(pAh + (size_t)r0 * K + k0 + c0,        &AsH[t * 8]);
    GLD_LDS16(pAh + (size_t)(r0 + 64) * K + k0 + c0, &AsH[2048 + t * 8]);
    GLD_LDS16(pBh + (size_t)r0 * K + k0 + c0,        &BsH[t * 8]);
    GLD_LDS16(pBh + (size_t)(r0 + 64) * K + k0 + c0, &BsH[2048 + t * 8]);
    if (!isV) {
      GLD_LDS16(pAl + (size_t)r0 * K + k0 + c0,        &AsL[t * 8]);
      GLD_LDS16(pAl + (size_t)(r0 + 64) * K + k0 + c0, &AsL[2048 + t * 8]);
      GLD_LDS16(pBl + (size_t)r0 * K + k0 + c0,        &BsL[t * 8]);
      GLD_LDS16(pBl + (size_t)(r0 + 64) * K + k0 + c0, &BsL[2048 + t * 8]);
    }
    __syncthreads();
    const int ao = (wr * 64 + (lane & 15)) * 32 + (lane >> 4) * 8;
    const int bo = (wc * 64 + (lane & 15)) * 32 + (lane >> 4) * 8;
    bf16x8v ah[4], bh_[4];
#pragma unroll
    for (int i = 0; i < 4; ++i) {
      ah[i]  = *(const bf16x8v*)&AsH[ao + i * 512];
      bh_[i] = *(const bf16x8v*)&BsH[bo + i * 512];
    }
    if (!isV) {
      bf16x8v al[4], bl_[4];
#pragma unroll
      for (int i = 0; i < 4; ++i) {
        al[i]  = *(const bf16x8v*)&AsL[ao + i * 512];
        bl_[i] = *(const bf16x8v*)&BsL[bo + i * 512];
      }
#pragma unroll
      for (int i = 0; i < 4; ++i)
#pragma unroll
        for (int j = 0; j < 4; ++j) {
          acc[i][j] = MFMA_BF16(ah[i], bh_[j], acc[i][j]);
          acc[i][j] = MFMA_BF16(ah[i], bl_[j], acc[i][j]);
          acc[i][j] = MFMA_BF16(al[i], bh_[j], acc[i][j]);
        }
    } else {
#pragma unroll
      for (int i = 0; i < 4; ++i)
#pragma unroll
        for (int j = 0; j < 4; ++j)
          acc[i][j] = MFMA_BF16(ah[i], bh_[j], acc[i][j]);
    }
  }
  // epilogue: split + scatter into (bh, s2, dh) layout (V transposed).
  // Q gets the 1/sqrt(D)=1/32 softmax scale folded in (exact pow-2 scale).
#pragma unroll
  for (int i = 0; i < 4; ++i)
#pragma unroll
    for (int j = 0; j < 4; ++j)
#pragma unroll
      for (int e = 0; e < 4; ++e) {
        const int m = brow + wr * 64 + i * 16 + ((lane >> 4) << 2) + e;
        const int n = bcol + wc * 64 + j * 16 + (lane & 15);
        float v = acc[i][j][e];
        const int b = m >> 11, s = m & 2047;
        const int c = n >> 10, d = n & 1023;
        const int bh_i = (b << 4) | (s >> 7);
        const int s2 = ((s & 127) << 4) | (d >> 6);
        const int dh = d & 63;
        if (c == 2) {
          Vt[((size_t)bh_i << 17) | ((size_t)dh << 11) | (size_t)s2] = __float2bfloat16(v);
        } else {
          if (c == 0) v *= 0.03125f;   // fold 1/sqrt(1024) into Q
          const size_t idx = ((size_t)bh_i << 17) | ((size_t)s2 << 6) | (size_t)dh;
          bf16 hv = __float2bfloat16(v);
          bf16 lv = __float2bfloat16(v - __bfloat162float(hv));
          if (c == 0) { Qhi[idx] = hv; Qlo[idx] = lv; }
          else        { Khi[idx] = hv; Klo[idx] = lv; }
        }
      }
}

// --------------------------------------------------------------------- attn --
// 1 wave / block; block = (bh, 32-row q-chunk). Longest chunks dispatch first.
// Swapped QK^T (st = K·Q^T); denominator via MFMA(P, ones); defer-max THR=8.
// Pipelined: K(t) preloaded; V(t) + K(t+1) issue before softmax so their L2
// latency hides under softmax+LDS+PV. P handoff fenced with lgkmcnt(0) only.
__global__ __launch_bounds__(64, 2) void attn_kernel(
    const bf16* __restrict__ Qhi, const bf16* __restrict__ Qlo,
    const bf16* __restrict__ Khi, const bf16* __restrict__ Klo,
    const bf16* __restrict__ Vt, bf16* __restrict__ Yp) {
  const int lane = threadIdx.x & 63;
  const int bh = blockIdx.x & 31;          // bh minor (bh%8 pins the XCD)
  const int c  = 63 - (blockIdx.x >> 5);   // chunk, longest (c=63) first
  const int b = bh >> 4, h = bh & 15;
  const size_t base = (size_t)bh << 17;    // * 2048*64
  const bf16* qh_p = Qhi + base;
  const bf16* ql_p = Qlo + base;
  const bf16* kh_p = Khi + base;
  const bf16* kl_p = Klo + base;
  const bf16* v_p  = Vt + base;            // (dh, s2) layout
  const int qbase = c << 5;
  const int l15 = lane & 15;
  const int lg  = lane >> 4;               // 0..3
  __shared__ __attribute__((aligned(16))) bf16 Plds[32][72];

  // Q fragments (B-operand: col = q-row = l15, k = dh), loaded once.
  bf16x8v qfh[2][2], qfl[2][2];
#pragma unroll
  for (int q2 = 0; q2 < 2; ++q2)
#pragma unroll
    for (int x2 = 0; x2 < 2; ++x2) {
      const size_t o = (size_t)(qbase + q2 * 16 + l15) * 64 + x2 * 32 + lg * 8;
      qfh[q2][x2] = *(const bf16x8v*)(qh_p + o);
      qfl[q2][x2] = *(const bf16x8v*)(ql_p + o);
    }
  bf16x8v ones8;
#pragma unroll
  for (int j = 0; j < 8; ++j) ones8[j] = (short)0x3F80;  // bf16 1.0

  f32x4 oac[2][4] = {};
  f32x4 oden[2] = {};
  float mrun[2] = {-3.0e38f, -3.0e38f};
  const float L2E = 1.4426950408889634f;
  const int nfull = c >> 1;                // diagonal tile index

  // K tile registers (single-buffered: tile t consumed by QK^T, then
  // overwritten by the t+1 prefetch — WAR on regs is free, in-order issue).
  bf16x8v kh0r[4], kh1r[4], kl0r[4], kl1r[4];
#define LOADK(kb_)                                                             \
  {                                                                            \
    const int _kb = (kb_);                                                     \
    _Pragma("unroll")                                                          \
    for (int kf = 0; kf < 4; ++kf) {                                           \
      const size_t ko = (size_t)(_kb + kf * 16 + l15) * 64 + lg * 8;           \
      kh0r[kf] = *(const bf16x8v*)(kh_p + ko);                                 \
      kh1r[kf] = *(const bf16x8v*)(kh_p + ko + 32);                            \
      kl0r[kf] = *(const bf16x8v*)(kl_p + ko);                                 \
      kl1r[kf] = *(const bf16x8v*)(kl_p + ko + 32);                            \
    }                                                                          \
  }
  LOADK(0);

  for (int kt = 0; kt <= nfull; ++kt) {
    const int kb = kt << 6;
    // ST = K · Q^T  (split: hh + h*l + l*h); Q pre-scaled by 1/32.
    f32x4 st[4][2] = {};
#pragma unroll
    for (int kf = 0; kf < 4; ++kf)
#pragma unroll
      for (int q2 = 0; q2 < 2; ++q2) {
        f32x4 a = st[kf][q2];
        a = MFMA_BF16(kh0r[kf], qfh[q2][0], a);
        a = MFMA_BF16(kh1r[kf], qfh[q2][1], a);
        a = MFMA_BF16(kh0r[kf], qfl[q2][0], a);
        a = MFMA_BF16(kh1r[kf], qfl[q2][1], a);
        a = MFMA_BF16(kl0r[kf], qfh[q2][0], a);
        a = MFMA_BF16(kl1r[kf], qfh[q2][1], a);
        st[kf][q2] = a;
      }
    // Issue V(t) loads now: ~softmax+LDS time to land before PV needs them.
    bf16x8v vreg[2][4];
#pragma unroll
    for (int x2 = 0; x2 < 2; ++x2)
#pragma unroll
      for (int df = 0; df < 4; ++df)
        vreg[x2][df] =
            *(const bf16x8v*)(v_p + (size_t)(df * 16 + l15) * 2048 + kb + x2 * 32 + lg * 8);
    // Prefetch K(t+1): lands during PV + next loop head.
    if (kt < nfull) LOADK(kb + 64);
    // causal mask only on the diagonal tile
    if (kt == nfull) {
#pragma unroll
      for (int kf = 0; kf < 4; ++kf)
#pragma unroll
        for (int q2 = 0; q2 < 2; ++q2)
#pragma unroll
          for (int e = 0; e < 4; ++e) {
            const int key = kb + kf * 16 + (lg << 2) + e;
            const int qr  = qbase + q2 * 16 + l15;
            if (key > qr) st[kf][q2][e] = -3.0e38f;
          }
    }
    // per-column tile max
    float tmax[2] = {-3.0e38f, -3.0e38f};
#pragma unroll
    for (int kf = 0; kf < 4; ++kf)
#pragma unroll
      for (int q2 = 0; q2 < 2; ++q2)
#pragma unroll
        for (int e = 0; e < 4; ++e)
          tmax[q2] = fmaxf(tmax[q2], st[kf][q2][e]);
#pragma unroll
    for (int q2 = 0; q2 < 2; ++q2) {
      tmax[q2] = fmaxf(tmax[q2], __shfl_xor(tmax[q2], 16));
      tmax[q2] = fmaxf(tmax[q2], __shfl_xor(tmax[q2], 32));
    }
    // defer-max: rescale only if some column grew past mrun+8
    const int ok = (tmax[0] <= mrun[0] + 8.0f) && (tmax[1] <= mrun[1] + 8.0f);
    if (!__all(ok)) {
      float sfac[2];
#pragma unroll
      for (int q2 = 0; q2 < 2; ++q2) {
        const float mn = fmaxf(mrun[q2], tmax[q2]);
        sfac[q2] = exp2f((mrun[q2] - mn) * L2E);
        mrun[q2] = mn;
      }
#pragma unroll
      for (int q2 = 0; q2 < 2; ++q2)
#pragma unroll
        for (int e = 0; e < 4; ++e) {
          const float so = __shfl(sfac[q2], (lg << 2) + e);  // col -> row bcast
          oden[q2][e] *= so;
#pragma unroll
          for (int df = 0; df < 4; ++df) oac[q2][df][e] *= so;
        }
    }
    // P = exp2((s - m)*log2e), packed b64 writes into LDS
    const float mL0 = mrun[0] * L2E, mL1 = mrun[1] * L2E;
#pragma unroll
    for (int kf = 0; kf < 4; ++kf)
#pragma unroll
      for (int q2 = 0; q2 < 2; ++q2) {
        const float mL = q2 ? mL1 : mL0;
        ushort4 pk;
        unsigned short* pp = &pk.x;
#pragma unroll
        for (int e = 0; e < 4; ++e) {
          const float pv = exp2f(fmaf(st[kf][q2][e], L2E, -mL));
          pp[e] = bf_bits(pv);
        }
        *(ushort4*)&Plds[q2 * 16 + l15][kf * 16 + (lg << 2)] = pk;
      }
    // FENCE the cross-lane LDS handoff (write->read): lgkmcnt(0) + compiler
    // ordering. Crucially this does NOT drain vmcnt — V(t)/K(t+1) loads stay
    // in flight. DS ops retire in wave order, so compiler order suffices.
    asm volatile("s_waitcnt lgkmcnt(0)" ::: "memory");
    __builtin_amdgcn_sched_barrier(0);
    // Read ALL P fragments, then a zero-cost compiler barrier so next tile's
    // ds_write cannot be scheduled above these reads (WAR, cross-lane).
    bf16x8v pa[2][2];
#pragma unroll
    for (int x2 = 0; x2 < 2; ++x2)
#pragma unroll
      for (int q2 = 0; q2 < 2; ++q2)
        pa[x2][q2] = *(const bf16x8v*)&Plds[q2 * 16 + l15][x2 * 32 + lg * 8];
    asm volatile("" ::: "memory");
    // O += P · V ; den += P · 1
#pragma unroll
    for (int x2 = 0; x2 < 2; ++x2) {
#pragma unroll
      for (int q2 = 0; q2 < 2; ++q2)
        oden[q2] = MFMA_BF16(pa[x2][q2], ones8, oden[q2]);
#pragma unroll
      for (int df = 0; df < 4; ++df)
#pragma unroll
        for (int q2 = 0; q2 < 2; ++q2)
          oac[q2][df] = MFMA_BF16(pa[x2][q2], vreg[x2][df], oac[q2][df]);
    }
  }
#undef LOADK
  // epilogue: oden rows match oac rows exactly -> no shuffles needed
#pragma unroll
  for (int q2 = 0; q2 < 2; ++q2) {
    float li[4];
#pragma unroll
    for (int e = 0; e < 4; ++e) li[e] = 1.0f / oden[q2][e];
#pragma unroll
    for (int df = 0; df < 4; ++df)
#pragma unroll
      for (int e = 0; e < 4; ++e) {
        const int qr = qbase + q2 * 16 + (lg << 2) + e;
        const int dh = df * 16 + l15;
        Yp[(size_t)(b * 2048 + qr) * 1024 + h * 64 + dh] =
            __float2bfloat16(oac[q2][df][e] * li[e]);
      }
  }
}

// ----------------------------------------------------------------- gemm_out --
// Y[m,n] = sum_k Yp[m,k]*Wo[n,k], M=4096 N=1024 K=1024, plain bf16, f32 out.
__global__ __launch_bounds__(256) void gemm_out(const bf16* __restrict__ A,
                                                const bf16* __restrict__ B,
                                                float* __restrict__ C) {
  const int K = 1024;
  const int NT = 8;  // 1024/128
  __shared__ __attribute__((aligned(16))) bf16 As[4096], Bs[4096];
  const int t = threadIdx.x;
  const int lane = t & 63;
  const int wave = t >> 6;
  const int wr = wave >> 1, wc = wave & 1;
  int bid = blockIdx.x;
  bid = (bid & 7) * (256 >> 3) + (bid >> 3);   // bijective XCD swizzle
  const int bm = bid / NT, bn = bid % NT;
  const int brow = bm * 128, bcol = bn * 128;
  const bf16* pA = A + (size_t)brow * K;
  const bf16* pB = B + (size_t)bcol * K;
  const int r0 = t >> 2;
  const int c0 = (t & 3) * 8;
  f32x4 acc[4][4] = {};
  for (int k0 = 0; k0 < K; k0 += 32) {
    __syncthreads();
    GLD_LDS16(pA + (size_t)r0 * K + k0 + c0,        &As[t * 8]);
    GLD_LDS16(pA + (size_t)(r0 + 64) * K + k0 + c0, &As[2048 + t * 8]);
    GLD_LDS16(pB + (size_t)r0 * K + k0 + c0,        &Bs[t * 8]);
    GLD_LDS16(pB + (size_t)(r0 + 64) * K + k0 + c0, &Bs[2048 + t * 8]);
    __syncthreads();
    bf16x8v af[4], bf_[4];
    const int ao = (wr * 64 + (lane & 15)) * 32 + (lane >> 4) * 8;
    const int bo = (wc * 64 + (lane & 15)) * 32 + (lane >> 4) * 8;
#pragma unroll
    for (int i = 0; i < 4; ++i) {
      af[i]  = *(const bf16x8v*)&As[ao + i * 512];
      bf_[i] = *(const bf16x8v*)&Bs[bo + i * 512];
    }
#pragma unroll
    for (int i = 0; i < 4; ++i)
#pragma unroll
      for (int j = 0; j < 4; ++j)
        acc[i][j] = MFMA_BF16(af[i], bf_[j], acc[i][j]);
  }
#pragma unroll
  for (int i = 0; i < 4; ++i)
#pragma unroll
    for (int j = 0; j < 4; ++j)
#pragma unroll
      for (int e = 0; e < 4; ++e) {
        const int m = brow + wr * 64 + i * 16 + ((lane >> 4) << 2) + e;
        const int n = bcol + wc * 64 + j * 16 + (lane & 15);
        C[(size_t)m * 1024 + n] = acc[i][j][e];
      }
}

// -------------------------------------------------------------------- launch --
extern "C" void kernel_launch(void* const* d_in, const int* in_sizes, int n_in,
                              void* d_out, int out_size, void* d_ws, size_t ws_size,
                              hipStream_t stream) {
  (void)in_sizes; (void)n_in; (void)out_size; (void)ws_size;
  const float* x    = (const float*)d_in[0];
  const float* wqkv = (const float*)d_in[1];
  const float* wo   = (const float*)d_in[2];
  float* out = (float*)d_out;

  const size_t NX = 4096ull * 1024;   // x / per-tensor QKV / Yp elements
  const size_t NW = 3072ull * 1024;   // W_qkv elements
  const size_t NO = 1024ull * 1024;   // W_o elements

  bf16* p = (bf16*)d_ws;
  bf16* xh  = p; p += NX;
  bf16* xl  = p; p += NX;
  bf16* wqh = p; p += NW;
  bf16* wql = p; p += NW;
  bf16* wob = p; p += NO;
  bf16* qhi = p; p += NX;
  bf16* qlo = p; p += NX;
  bf16* khi = p; p += NX;
  bf16* klo = p; p += NX;
  bf16* vt  = p; p += NX;
  bf16* yp  = p; p += NX;   // total ~78 MB of workspace

  hipLaunchKernelGGL(cvt_split, dim3(NX / 1024), dim3(256), 0, stream, x, xh, xl, (int)NX);
  hipLaunchKernelGGL(cvt_split, dim3(NW / 1024), dim3(256), 0, stream, wqkv, wqh, wql, (int)NW);
  hipLaunchKernelGGL(cvt_plain, dim3(NO / 1024), dim3(256), 0, stream, wo, wob, (int)NO);
  hipLaunchKernelGGL(gemm_qkv, dim3(32 * 24), dim3(256), 0, stream,
                     xh, xl, wqh, wql, qhi, qlo, khi, klo, vt);
  hipLaunchKernelGGL(attn_kernel, dim3(2048), dim3(64), 0, stream,
                     qhi, qlo, khi, klo, vt, yp);
  hipLaunchKernelGGL(gemm_out, dim3(32 * 8), dim3(256), 0, stream, yp, wob, out);
}